// Round 7
// baseline (275.102 us; speedup 1.0000x reference)
//
#include <hip/hip_runtime.h>
#include <hip/hip_bf16.h>
#include <math.h>

// Gate: logits = x @ W^T ; scores = sigmoid(logits)+bias ; top-8 ; normalize *2.5
// T=16384, H=K=4096, E=256.
// fp32 GEMM via EXACT 3-way bf16 truncation split (x = h1+h2+h3 bit-exact),
// 6 cross products (11,12,21,22,13,31) -> rel error ~2^-24.
// Round 7: barrier-at-top pipeline -- ONE __syncthreads per K-step, placed so
// every global load (A->regs, B->LDS via gll) is a full compute phase old when
// the drain happens. B double-buffered (96 KiB), A in registers, BM=128 BN=128
// BK=64, 512 threads (8 waves = 2/SIMD), 1 block/CU, grid=256.

using bf16x4 = __attribute__((ext_vector_type(4))) short;
using bf16x8 = __attribute__((ext_vector_type(8))) short;
using f32x4  = __attribute__((ext_vector_type(4))) float;

constexpr int E_EXPERTS = 256;
constexpr int KDIM      = 4096;
constexpr int TOPK      = 8;
constexpr float SCALE   = 2.5f;

constexpr int BM = 128, BN = 128, BK = 64, NT = 512;
constexpr int NSTEP = KDIM / BK;   // 64
constexpr int BUFSH = 3 * 8192;    // shorts per buffer (48 KiB): 3 lev x [128 e][64 k]
// Row = 64 shorts (128 B) = 8 chunks of 8 bf16. Physical chunk pc of row e holds
// logical k-chunk pc ^ (e&7): a 16-lane MFMA group's ds_read_b128 spreads over
// 8 chunk slots -> 2 lanes/bank = free (R6 measured 0 conflicts). gll dest is
// LINEAR; the global source column carries the same XOR (both-sides rule).

__device__ __forceinline__ void load_lds16(const short* g, short* l) {
    auto gp = (const __attribute__((address_space(1))) short*)g;
    auto lp = (__attribute__((address_space(3))) short*)(uintptr_t)l;
    __builtin_amdgcn_global_load_lds(gp, lp, 16, 0, 0);
}

// Exact truncation split: x == bf16(h1)+bf16(h2)+bf16(h3) (normal fp32).
__device__ __forceinline__ void split1(float x, short& h1, short& h2, short& h3) {
    unsigned u = __float_as_uint(x);
    h1 = (short)(u >> 16);
    float r1 = x - __uint_as_float(u & 0xFFFF0000u);
    unsigned u1 = __float_as_uint(r1);
    h2 = (short)(u1 >> 16);
    float r2 = r1 - __uint_as_float(u1 & 0xFFFF0000u);
    h3 = (short)(__float_as_uint(r2) >> 16);
}

__global__ void wsplit_kernel(const float* __restrict__ W, short* __restrict__ W1,
                              short* __restrict__ W2, short* __restrict__ W3) {
    int i = blockIdx.x * 256 + threadIdx.x;   // float4 index
    float4 w = ((const float4*)W)[i];
    bf16x4 s1, s2, s3;
    short a, b, c;
    split1(w.x, a, b, c); s1.x = a; s2.x = b; s3.x = c;
    split1(w.y, a, b, c); s1.y = a; s2.y = b; s3.y = c;
    split1(w.z, a, b, c); s1.z = a; s2.z = b; s3.z = c;
    split1(w.w, a, b, c); s1.w = a; s2.w = b; s3.w = c;
    ((bf16x4*)W1)[i] = s1;
    ((bf16x4*)W2)[i] = s2;
    ((bf16x4*)W3)[i] = s3;
}

__global__ __launch_bounds__(NT, 2) void gate_gemm(
    const float* __restrict__ X,
    const short* __restrict__ W1, const short* __restrict__ W2, const short* __restrict__ W3,
    const float* __restrict__ Bias, float* __restrict__ S) {
    __shared__ short lds[2 * BUFSH];   // 96 KiB -> 1 block/CU

    const int tid  = threadIdx.x;
    const int lane = tid & 63;
    const int w    = tid >> 6;        // wave 0..7
    const int wm   = w >> 1;          // 0..3 : 32-token quarter
    const int wn   = w & 1;           // 0..1 : 64-expert half
    const int g    = lane >> 4;       // k-chunk within 32-k group

    // Bijective XCD swizzle (grid=256, 256%8==0): each XCD gets 32 consecutive
    // logical ids; the two expert-halves of a token tile are adjacent -> same
    // XCD -> X L2-reuse.
    const int p       = blockIdx.x;
    const int cpx     = gridDim.x >> 3;              // 32
    const int logical = (p & 7) * cpx + (p >> 3);
    const int tok0 = (logical >> 1) * BM;
    const int e0   = (logical & 1) * BN;

    // ---- A (in-register): frag (mf,ks2): row = wm*32+mf*16+(lane&15),
    //      k = ks*64 + ks2*32 + g*8 .. +7  (8 consecutive fp32 per lane).
    const float* xa[2][2];
#pragma unroll
    for (int mf = 0; mf < 2; ++mf)
#pragma unroll
        for (int ks2 = 0; ks2 < 2; ++ks2)
            xa[mf][ks2] = X + (size_t)(tok0 + wm * 32 + mf * 16 + (lane & 15)) * KDIM
                            + ks2 * 32 + g * 8;

    // ---- B staging: 1024 16B-units per level per buffer, 2 per thread per level.
    int bsrc[2], bdst[2];   // short offsets (k0, lev, buf added at use)
#pragma unroll
    for (int j = 0; j < 2; ++j) {
        int f = j * 512 + tid;
        int e = f >> 3, pc = f & 7;
        int c = pc ^ (e & 7);
        bsrc[j] = (e0 + e) * KDIM + c * 8;
        bdst[j] = f * 8;
    }

    // ---- B compute-side read offsets (shorts, within level region)
    int bro[4][2];   // [nf][ks2]
#pragma unroll
    for (int nf = 0; nf < 4; ++nf) {
        int e = wn * 64 + nf * 16 + (lane & 15);
#pragma unroll
        for (int ks2 = 0; ks2 < 2; ++ks2)
            bro[nf][ks2] = e * 64 + (((ks2 << 2) + g) ^ (e & 7)) * 8;
    }

    auto stage = [&](int bufOff, int k0) {
#pragma unroll
        for (int j = 0; j < 2; ++j) {
            load_lds16(W1 + (size_t)bsrc[j] + k0, &lds[bufOff + 0 * 8192 + bdst[j]]);
            load_lds16(W2 + (size_t)bsrc[j] + k0, &lds[bufOff + 1 * 8192 + bdst[j]]);
            load_lds16(W3 + (size_t)bsrc[j] + k0, &lds[bufOff + 2 * 8192 + bdst[j]]);
        }
    };

    float4 raw[2][2][2];   // [mf][ks2][half]
    auto loadA = [&](int ks) {
#pragma unroll
        for (int mf = 0; mf < 2; ++mf)
#pragma unroll
            for (int ks2 = 0; ks2 < 2; ++ks2) {
                const float* s = xa[mf][ks2] + (size_t)ks * BK;
                raw[mf][ks2][0] = *(const float4*)s;
                raw[mf][ks2][1] = *(const float4*)(s + 4);
            }
    };

    f32x4 acc[2][4];
#pragma unroll
    for (int i = 0; i < 2; ++i)
#pragma unroll
        for (int j = 0; j < 4; ++j) acc[i][j] = f32x4{0.f, 0.f, 0.f, 0.f};

    // ---- prologue: issue step-0 loads; first barrier pays their latency once
    stage(0, 0);
    loadA(0);

    int buf = 0;
    for (int ks = 0; ks < NSTEP; ++ks) {
        // Barrier AT TOP: all in-flight loads were issued a full compute phase
        // ago -> vmcnt drain is free. Also fences: all waves finished reading
        // the buffer that this step's stage() will overwrite.
        __syncthreads();

        // split A(ks) (raw, loaded last step) into 3 bf16 levels, lane-local
        bf16x8 fa[2][2][3];   // [mf][ks2][lev]
#pragma unroll
        for (int mf = 0; mf < 2; ++mf)
#pragma unroll
            for (int ks2 = 0; ks2 < 2; ++ks2) {
                float v[8] = {raw[mf][ks2][0].x, raw[mf][ks2][0].y,
                              raw[mf][ks2][0].z, raw[mf][ks2][0].w,
                              raw[mf][ks2][1].x, raw[mf][ks2][1].y,
                              raw[mf][ks2][1].z, raw[mf][ks2][1].w};
                bf16x8 s1, s2, s3;
#pragma unroll
                for (int j = 0; j < 8; ++j) {
                    short h1, h2, h3; split1(v[j], h1, h2, h3);
                    s1[j] = h1; s2[j] = h2; s3[j] = h3;
                }
                fa[mf][ks2][0] = s1; fa[mf][ks2][1] = s2; fa[mf][ks2][2] = s3;
            }

        // issue next step's loads NOW -- they ride under this step's compute
        if (ks + 1 < NSTEP) {
            loadA(ks + 1);                        // A(ks+1) -> regs
            stage((buf ^ 1) * BUFSH, (ks + 1) * BK);  // B(ks+1) -> other buffer
        }

        // compute from buf (its gll completed; drained at the top barrier)
        const int bo = buf * BUFSH;
#pragma unroll
        for (int nf = 0; nf < 4; ++nf) {
            bf16x8 fb[3][2];   // [lev][ks2]
#pragma unroll
            for (int lev = 0; lev < 3; ++lev)
#pragma unroll
                for (int ks2 = 0; ks2 < 2; ++ks2)
                    fb[lev][ks2] = *(const bf16x8*)&lds[bo + lev * 8192 + bro[nf][ks2]];
#pragma unroll
            for (int mf = 0; mf < 2; ++mf) {
                f32x4 c = acc[mf][nf];
#pragma unroll
                for (int ks2 = 0; ks2 < 2; ++ks2) {
                    c = __builtin_amdgcn_mfma_f32_16x16x32_bf16(fa[mf][ks2][0], fb[0][ks2], c, 0, 0, 0);
                    c = __builtin_amdgcn_mfma_f32_16x16x32_bf16(fa[mf][ks2][0], fb[1][ks2], c, 0, 0, 0);
                    c = __builtin_amdgcn_mfma_f32_16x16x32_bf16(fa[mf][ks2][1], fb[0][ks2], c, 0, 0, 0);
                    c = __builtin_amdgcn_mfma_f32_16x16x32_bf16(fa[mf][ks2][1], fb[1][ks2], c, 0, 0, 0);
                    c = __builtin_amdgcn_mfma_f32_16x16x32_bf16(fa[mf][ks2][0], fb[2][ks2], c, 0, 0, 0);
                    c = __builtin_amdgcn_mfma_f32_16x16x32_bf16(fa[mf][ks2][2], fb[0][ks2], c, 0, 0, 0);
                }
                acc[mf][nf] = c;
            }
        }
        buf ^= 1;
    }

    // ---- epilogue: sigmoid + bias -> scores
    // C/D layout: col(expert) = lane&15, row(token) = (lane>>4)*4 + v.
#pragma unroll
    for (int mf = 0; mf < 2; ++mf)
#pragma unroll
        for (int nf = 0; nf < 4; ++nf) {
            const int ec = e0 + wn * 64 + nf * 16 + (lane & 15);
            const float bv = Bias[ec];
#pragma unroll
            for (int v = 0; v < 4; ++v) {
                const int tr = tok0 + wm * 32 + mf * 16 + (lane >> 4) * 4 + v;
                S[(size_t)tr * E_EXPERTS + ec] = 1.0f / (1.0f + expf(-acc[mf][nf][v])) + bv;
            }
        }
}

// One wave per token: 256 scores, 4/lane; 8 rounds of butterfly argmax.
// Tie-break: higher value wins; equal value -> lower index (matches lax.top_k / np).
__global__ __launch_bounds__(256) void gate_topk(
    const float* __restrict__ S, float* __restrict__ outIdx,
    float* __restrict__ outW, int T) {
    const int wave = threadIdx.x >> 6;
    const int lane = threadIdx.x & 63;
    const int t    = blockIdx.x * 4 + wave;
    if (t >= T) return;

    const float* row = S + (size_t)t * E_EXPERTS;
    float v[4];
    int   idx[4];
#pragma unroll
    for (int j = 0; j < 4; ++j) {
        idx[j] = lane + 64 * j;
        v[j]   = row[idx[j]];
    }

    float tv[TOPK];
    int   ti[TOPK];
#pragma unroll
    for (int k = 0; k < TOPK; ++k) {
        float bv = v[0];
        int   bi = idx[0];
#pragma unroll
        for (int j = 1; j < 4; ++j)
            if (v[j] > bv) { bv = v[j]; bi = idx[j]; }
#pragma unroll
        for (int off = 1; off < 64; off <<= 1) {
            float ov = __shfl_xor(bv, off);
            int   oi = __shfl_xor(bi, off);
            if (ov > bv || (ov == bv && oi < bi)) { bv = ov; bi = oi; }
        }
        tv[k] = bv;
        ti[k] = bi;
#pragma unroll
        for (int j = 0; j < 4; ++j)
            if (idx[j] == bi) v[j] = -INFINITY;
    }

    float denom = 0.0f;
#pragma unroll
    for (int k = 0; k < TOPK; ++k) denom += tv[k];
    denom += 1e-20f;

#pragma unroll
    for (int k = 0; k < TOPK; ++k) {
        if (lane == k) {
            outIdx[(size_t)t * TOPK + k] = (float)ti[k];
            outW[(size_t)t * TOPK + k]   = (tv[k] / denom) * SCALE;
        }
    }
}

extern "C" void kernel_launch(void* const* d_in, const int* in_sizes, int n_in,
                              void* d_out, int out_size, void* d_ws, size_t ws_size,
                              hipStream_t stream) {
    const float* x    = (const float*)d_in[0];
    const float* w    = (const float*)d_in[1];
    const float* bias = (const float*)d_in[2];

    const int T = in_sizes[0] / KDIM;   // 16384

    float* S  = (float*)d_ws;                                        // [T][256] f32, 16 MiB
    short* W1 = (short*)((char*)d_ws + (size_t)T * E_EXPERTS * 4);   // 3 x 2 MiB bf16
    short* W2 = W1 + (size_t)E_EXPERTS * KDIM;
    short* W3 = W2 + (size_t)E_EXPERTS * KDIM;

    float* outIdx = (float*)d_out;                  // idx chunk (as float values)
    float* outW   = outIdx + (size_t)T * TOPK;      // weight chunk

    wsplit_kernel<<<(E_EXPERTS * KDIM / 4) / 256, 256, 0, stream>>>(w, W1, W2, W3);
    gate_gemm<<<(T / BM) * (E_EXPERTS / BN), NT, 0, stream>>>(x, W1, W2, W3, bias, S);
    gate_topk<<<T / 4, 256, 0, stream>>>(S, outIdx, outW, T);
}

// Round 8
// 240.344 us; speedup vs baseline: 1.1446x; 1.1446x over previous
//
#include <hip/hip_runtime.h>
#include <hip/hip_bf16.h>
#include <math.h>

// Gate: logits = x @ W^T ; scores = sigmoid(logits)+bias ; top-8 ; normalize *2.5
// T=16384, H=K=4096, E=256.
// fp32 GEMM via EXACT 3-way bf16 truncation split (x = h1+h2+h3 bit-exact),
// 6 cross products (11,12,21,22,13,31) -> rel error ~2^-24.
// Round 8: 32x32x16 MFMA (wave tile 32x64) + half-K 3-region LDS pipeline:
// A single-buffered (fa -> regs in phase a, A(k+1) written in phase b),
// B in two half-K buffers filled one phase ahead. 72 KiB -> 2 blocks/CU,
// NT=256, grid=512, 2 barriers/step, XCD pair-swizzle.

using bf16x4 = __attribute__((ext_vector_type(4))) short;
using bf16x8 = __attribute__((ext_vector_type(8))) short;
using f32x16 = __attribute__((ext_vector_type(16))) float;

constexpr int E_EXPERTS = 256;
constexpr int KDIM      = 4096;
constexpr int TOPK      = 8;
constexpr float SCALE   = 2.5f;

constexpr int BM = 64, BN = 128, BK = 64, NT = 256;
constexpr int NSTEP = KDIM / BK;   // 64
// LDS (shorts): A at 0: [3 lev][64 r][8 pc][8]  (12288 sh, 24 KiB)
//   logical chunk c of row r stored at pc = c ^ (r&7)  -> 32 B/bank on b128 reads
// B half-buffers at 12288 + h*12288: [3 lev][128 e][4 pc][8] (24 KiB each)
//   logical chunk c (of K=32 half) stored at pc = c ^ ((e>>1)&3) -> 32 B/bank

__device__ __forceinline__ void load_lds16(const short* g, short* l) {
    auto gp = (const __attribute__((address_space(1))) short*)g;
    auto lp = (__attribute__((address_space(3))) short*)(uintptr_t)l;
    __builtin_amdgcn_global_load_lds(gp, lp, 16, 0, 0);
}

// Exact truncation split: x == bf16(h1)+bf16(h2)+bf16(h3) (normal fp32).
__device__ __forceinline__ void split1(float x, short& h1, short& h2, short& h3) {
    unsigned u = __float_as_uint(x);
    h1 = (short)(u >> 16);
    float r1 = x - __uint_as_float(u & 0xFFFF0000u);
    unsigned u1 = __float_as_uint(r1);
    h2 = (short)(u1 >> 16);
    float r2 = r1 - __uint_as_float(u1 & 0xFFFF0000u);
    h3 = (short)(__float_as_uint(r2) >> 16);
}

__global__ void wsplit_kernel(const float* __restrict__ W, short* __restrict__ W1,
                              short* __restrict__ W2, short* __restrict__ W3) {
    int i = blockIdx.x * 256 + threadIdx.x;   // float4 index
    float4 w = ((const float4*)W)[i];
    bf16x4 s1, s2, s3;
    short a, b, c;
    split1(w.x, a, b, c); s1.x = a; s2.x = b; s3.x = c;
    split1(w.y, a, b, c); s1.y = a; s2.y = b; s3.y = c;
    split1(w.z, a, b, c); s1.z = a; s2.z = b; s3.z = c;
    split1(w.w, a, b, c); s1.w = a; s2.w = b; s3.w = c;
    ((bf16x4*)W1)[i] = s1;
    ((bf16x4*)W2)[i] = s2;
    ((bf16x4*)W3)[i] = s3;
}

__global__ __launch_bounds__(NT, 2) void gate_gemm(
    const float* __restrict__ X,
    const short* __restrict__ W1, const short* __restrict__ W2, const short* __restrict__ W3,
    const float* __restrict__ Bias, float* __restrict__ S) {
    __shared__ short lds[36864];   // 72 KiB -> 2 blocks/CU
    constexpr int B0 = 12288, B1 = 24576;

    const int tid  = threadIdx.x;
    const int lane = tid & 63;
    const int w    = tid >> 6;        // wave 0..3
    const int wm   = w >> 1;          // 0..1 : 32-token half
    const int wn   = w & 1;           // 0..1 : 64-expert half

    // XCD swizzle (grid=512, 512%8==0 -> bijective): expert-halves adjacent.
    const int p       = blockIdx.x;
    const int cpx     = gridDim.x >> 3;              // 64
    const int logical = (p & 7) * cpx + (p >> 3);
    const int tok0 = (logical >> 1) * BM;
    const int e0   = (logical & 1) * BN;

    // ---- A staging: thread owns rows ar0, ar0+32, phys chunk apc.
    const int ar0   = tid >> 3;                      // 0..31
    const int apc   = tid & 7;
    const int acsrc = apc ^ (ar0 & 7);               // pre-permuted global chunk
    const float* xrow0 = X + (size_t)(tok0 + ar0) * KDIM + acsrc * 8;
    const float* xrow1 = xrow0 + (size_t)32 * KDIM;
    const int aw0 = (ar0 * 8 + apc) * 8;             // A write offsets (per lev)
    const int aw1 = ((ar0 + 32) * 8 + apc) * 8;

    // ---- B staging: 6 gll/thread (3 lev x 2); per j: 16B-unit f = j*256+tid.
    int bsrc[2], bdst[2];
#pragma unroll
    for (int j = 0; j < 2; ++j) {
        int f = j * 256 + tid;
        int e = f >> 2, pc = f & 3;
        int c = pc ^ ((e >> 1) & 3);
        bsrc[j] = (e0 + e) * KDIM + c * 8;           // + kOff at use
        bdst[j] = f * 8;                             // + bufBase + lev*4096
    }

    // ---- fragment read offsets
    // A (32x32x16 operand): row = wm*32+(lane&31); chunk c = ks4*2 + (lane>>5)
    int aro[4];
    {
        int r = wm * 32 + (lane & 31);
#pragma unroll
        for (int ks4 = 0; ks4 < 4; ++ks4) {
            int c = ks4 * 2 + (lane >> 5);
            aro[ks4] = r * 64 + (c ^ (r & 7)) * 8;
        }
    }
    // B: e = wn*64+nt*32+(lane&31); within-half chunk c = k2*2 + (lane>>5)
    int bro[2][2];
#pragma unroll
    for (int nt = 0; nt < 2; ++nt) {
        int e = wn * 64 + nt * 32 + (lane & 31);
#pragma unroll
        for (int k2 = 0; k2 < 2; ++k2) {
            int c = k2 * 2 + (lane >> 5);
            bro[nt][k2] = e * 32 + (c ^ ((e >> 1) & 3)) * 8;
        }
    }

    auto stageB = [&](int bufBase, int kOff) {
#pragma unroll
        for (int j = 0; j < 2; ++j) {
            load_lds16(W1 + (size_t)bsrc[j] + kOff, &lds[bufBase + 0 * 4096 + bdst[j]]);
            load_lds16(W2 + (size_t)bsrc[j] + kOff, &lds[bufBase + 1 * 4096 + bdst[j]]);
            load_lds16(W3 + (size_t)bsrc[j] + kOff, &lds[bufBase + 2 * 4096 + bdst[j]]);
        }
    };

    float4 raw[4];   // rows ar0 (raw[0..1]) and ar0+32 (raw[2..3]), 8 floats each
    auto loadAraw = [&](int ks) {
        raw[0] = *(const float4*)(xrow0 + (size_t)ks * BK);
        raw[1] = *(const float4*)(xrow0 + (size_t)ks * BK + 4);
        raw[2] = *(const float4*)(xrow1 + (size_t)ks * BK);
        raw[3] = *(const float4*)(xrow1 + (size_t)ks * BK + 4);
    };
    auto splitWriteA = [&]() {
#pragma unroll
        for (int h = 0; h < 2; ++h) {
            float v[8] = {raw[2 * h].x, raw[2 * h].y, raw[2 * h].z, raw[2 * h].w,
                          raw[2 * h + 1].x, raw[2 * h + 1].y, raw[2 * h + 1].z, raw[2 * h + 1].w};
            bf16x8 s1, s2, s3;
#pragma unroll
            for (int j = 0; j < 8; ++j) {
                short h1, h2, h3; split1(v[j], h1, h2, h3);
                s1[j] = h1; s2[j] = h2; s3[j] = h3;
            }
            const int aw = h ? aw1 : aw0;
            *(bf16x8*)&lds[0 * 4096 + aw] = s1;
            *(bf16x8*)&lds[1 * 4096 + aw] = s2;
            *(bf16x8*)&lds[2 * 4096 + aw] = s3;
        }
    };

    f32x16 acc[2];
#pragma unroll
    for (int nt = 0; nt < 2; ++nt)
#pragma unroll
        for (int j = 0; j < 16; ++j) acc[nt][j] = 0.0f;

    bf16x8 fa[3][4];
    auto readFa = [&]() {
#pragma unroll
        for (int lev = 0; lev < 3; ++lev)
#pragma unroll
            for (int ks4 = 0; ks4 < 4; ++ks4)
                fa[lev][ks4] = *(const bf16x8*)&lds[lev * 4096 + aro[ks4]];
    };

    auto computeHalf = [&](int bufBase, int kap) {   // kap = half index 0/1
#pragma unroll
        for (int nt = 0; nt < 2; ++nt) {
            bf16x8 fb[3][2];
#pragma unroll
            for (int lev = 0; lev < 3; ++lev)
#pragma unroll
                for (int k2 = 0; k2 < 2; ++k2)
                    fb[lev][k2] = *(const bf16x8*)&lds[bufBase + lev * 4096 + bro[nt][k2]];
            f32x16 c = acc[nt];
#pragma unroll
            for (int k2 = 0; k2 < 2; ++k2) {
                const int ks4 = kap * 2 + k2;
                c = __builtin_amdgcn_mfma_f32_32x32x16_bf16(fa[0][ks4], fb[0][k2], c, 0, 0, 0);
                c = __builtin_amdgcn_mfma_f32_32x32x16_bf16(fa[0][ks4], fb[1][k2], c, 0, 0, 0);
                c = __builtin_amdgcn_mfma_f32_32x32x16_bf16(fa[1][ks4], fb[0][k2], c, 0, 0, 0);
                c = __builtin_amdgcn_mfma_f32_32x32x16_bf16(fa[1][ks4], fb[1][k2], c, 0, 0, 0);
                c = __builtin_amdgcn_mfma_f32_32x32x16_bf16(fa[0][ks4], fb[2][k2], c, 0, 0, 0);
                c = __builtin_amdgcn_mfma_f32_32x32x16_bf16(fa[2][ks4], fb[0][k2], c, 0, 0, 0);
            }
            acc[nt] = c;
        }
    };

    // ---- prologue: fill B0 with h0(0), split A(0); one-time latency.
    stageB(B0, 0);
    loadAraw(0);
    splitWriteA();            // waits raw(0) (and thus the earlier gll) once
    __syncthreads();          // publishes A(0); B0 drained

    for (int ks = 0; ks < NSTEP; ++ks) {
        // ---- phase a: fill B1 with h1(ks) (readers done at bar_b(ks-1));
        //      prefetch raw A(ks+1); read fa; compute h0 from B0.
        stageB(B1, ks * BK + 32);
        if (ks + 1 < NSTEP) loadAraw(ks + 1);
        readFa();
        computeHalf(B0, 0);
        __syncthreads();      // bar_a: drains B1 gll (1 phase old) + raw loads

        // ---- phase b: fill B0 with h0(ks+1) (readers done at bar_a);
        //      write A(ks+1) (fa of A(ks) is in regs); compute h1 from B1.
        if (ks + 1 < NSTEP) {
            stageB(B0, (ks + 1) * BK);
            splitWriteA();
        }
        computeHalf(B1, 1);
        __syncthreads();      // bar_b: publishes A(ks+1); drains B0 gll
    }

    // ---- epilogue: sigmoid + bias -> scores
    // 32x32 C/D: col(expert) = lane&31, row = (reg&3) + 8*(reg>>2) + 4*(lane>>5).
#pragma unroll
    for (int nt = 0; nt < 2; ++nt) {
        const int ec = e0 + wn * 64 + nt * 32 + (lane & 31);
        const float bv = Bias[ec];
#pragma unroll
        for (int reg = 0; reg < 16; ++reg) {
            const int tr = tok0 + wm * 32 + (reg & 3) + 8 * (reg >> 2) + 4 * (lane >> 5);
            S[(size_t)tr * E_EXPERTS + ec] = 1.0f / (1.0f + expf(-acc[nt][reg])) + bv;
        }
    }
}

// One wave per token: 256 scores, 4/lane; 8 rounds of butterfly argmax.
// Tie-break: higher value wins; equal value -> lower index (matches lax.top_k / np).
__global__ __launch_bounds__(256) void gate_topk(
    const float* __restrict__ S, float* __restrict__ outIdx,
    float* __restrict__ outW, int T) {
    const int wave = threadIdx.x >> 6;
    const int lane = threadIdx.x & 63;
    const int t    = blockIdx.x * 4 + wave;
    if (t >= T) return;

    const float* row = S + (size_t)t * E_EXPERTS;
    float v[4];
    int   idx[4];
#pragma unroll
    for (int j = 0; j < 4; ++j) {
        idx[j] = lane + 64 * j;
        v[j]   = row[idx[j]];
    }

    float tv[TOPK];
    int   ti[TOPK];
#pragma unroll
    for (int k = 0; k < TOPK; ++k) {
        float bv = v[0];
        int   bi = idx[0];
#pragma unroll
        for (int j = 1; j < 4; ++j)
            if (v[j] > bv) { bv = v[j]; bi = idx[j]; }
#pragma unroll
        for (int off = 1; off < 64; off <<= 1) {
            float ov = __shfl_xor(bv, off);
            int   oi = __shfl_xor(bi, off);
            if (ov > bv || (ov == bv && oi < bi)) { bv = ov; bi = oi; }
        }
        tv[k] = bv;
        ti[k] = bi;
#pragma unroll
        for (int j = 0; j < 4; ++j)
            if (idx[j] == bi) v[j] = -INFINITY;
    }

    float denom = 0.0f;
#pragma unroll
    for (int k = 0; k < TOPK; ++k) denom += tv[k];
    denom += 1e-20f;

#pragma unroll
    for (int k = 0; k < TOPK; ++k) {
        if (lane == k) {
            outIdx[(size_t)t * TOPK + k] = (float)ti[k];
            outW[(size_t)t * TOPK + k]   = (tv[k] / denom) * SCALE;
        }
    }
}

extern "C" void kernel_launch(void* const* d_in, const int* in_sizes, int n_in,
                              void* d_out, int out_size, void* d_ws, size_t ws_size,
                              hipStream_t stream) {
    const float* x    = (const float*)d_in[0];
    const float* w    = (const float*)d_in[1];
    const float* bias = (const float*)d_in[2];

    const int T = in_sizes[0] / KDIM;   // 16384

    float* S  = (float*)d_ws;                                        // [T][256] f32, 16 MiB
    short* W1 = (short*)((char*)d_ws + (size_t)T * E_EXPERTS * 4);   // 3 x 2 MiB bf16
    short* W2 = W1 + (size_t)E_EXPERTS * KDIM;
    short* W3 = W2 + (size_t)E_EXPERTS * KDIM;

    float* outIdx = (float*)d_out;                  // idx chunk (as float values)
    float* outW   = outIdx + (size_t)T * TOPK;      // weight chunk

    wsplit_kernel<<<(E_EXPERTS * KDIM / 4) / 256, 256, 0, stream>>>(w, W1, W2, W3);
    gate_gemm<<<(T / BM) * (E_EXPERTS / BN), NT, 0, stream>>>(x, W1, W2, W3, bias, S);
    gate_topk<<<T / 4, 256, 0, stream>>>(S, outIdx, outW, T);
}

// Round 9
// 217.623 us; speedup vs baseline: 1.2641x; 1.1044x over previous
//
#include <hip/hip_runtime.h>
#include <hip/hip_bf16.h>
#include <math.h>

// Gate: logits = x @ W^T ; scores = sigmoid(logits)+bias ; top-8 ; normalize *2.5
// T=16384, H=K=4096, E=256.
// Round 9: fp32 GEMM via SCALED f16 2-level split, 3 products.
//   x = h1 + 2^-12 h2 + r,  h1 = rne_f16(x), h2 = rne_f16((x-h1)*4096): both
//   levels f16-NORMAL (fixes R5's denormal flush). W side adds guard w1=0 when
//   |w| < 2^-14. logit = acc11 + 2^-12*(acc12+acc21); h2*w2 (2^-24) dropped.
//   Residual noise ~4e-7 in logits ~ fp32 reference noise. MFMA work 103 GF
//   (was 206) -> 41 us MFMA floor == HBM floor (X 256 MB).
// Structure: A in regs (on-the-fly split), B (2 f16 levels) double-buffered in
// LDS (64 KiB), barrier-at-top single sync/step, NT=256, block 64x128 (waves
// 32x64, 32x32x16 MFMA), grid 512 -> 2 blocks/CU, XCD pair-swizzle.

using f16x8  = __attribute__((ext_vector_type(8))) _Float16;
using f32x16 = __attribute__((ext_vector_type(16))) float;

constexpr int E_EXPERTS = 256;
constexpr int KDIM      = 4096;
constexpr int TOPK      = 8;
constexpr float SCALE   = 2.5f;

constexpr int BM = 64, BN = 128, BK = 64, NT = 256;
constexpr int NSTEP = KDIM / BK;   // 64
constexpr float F16_MIN_NORMAL = 6.1035156e-5f;
// LDS: 2 buffers x 2 levels x [128 e][64 k] f16 = 32768 shorts = 64 KiB.
// Row = 64 shorts (128 B) = 8 chunks of 8 f16. Physical chunk pc of row e holds
// logical chunk pc ^ (e&7): any aligned 8-lane group of a ds_read_b128 covers
// all 8 chunk slots -> all 32 banks -> conflict-free (R2/R6-verified pattern).
// gll dest LINEAR (wave-uniform base + lane*16); global source pre-permuted.

__device__ __forceinline__ void load_lds16(const short* g, short* l) {
    auto gp = (const __attribute__((address_space(1))) short*)g;
    auto lp = (__attribute__((address_space(3))) short*)(uintptr_t)l;
    __builtin_amdgcn_global_load_lds(gp, lp, 16, 0, 0);
}

// One-time W split (RNE, scaled level 2, denormal guard on level 1).
__global__ void wsplit_kernel(const float* __restrict__ W, short* __restrict__ W1,
                              short* __restrict__ W2) {
    int i = blockIdx.x * 256 + threadIdx.x;   // float4 index
    float4 w = ((const float4*)W)[i];
    float v[4] = {w.x, w.y, w.z, w.w};
    short o1[4], o2[4];
#pragma unroll
    for (int j = 0; j < 4; ++j) {
        _Float16 h1 = (fabsf(v[j]) >= F16_MIN_NORMAL) ? (_Float16)v[j] : (_Float16)0.0f;
        _Float16 h2 = (_Float16)((v[j] - (float)h1) * 4096.0f);
        o1[j] = __builtin_bit_cast(short, h1);
        o2[j] = __builtin_bit_cast(short, h2);
    }
    ((short4*)W1)[i] = make_short4(o1[0], o1[1], o1[2], o1[3]);
    ((short4*)W2)[i] = make_short4(o2[0], o2[1], o2[2], o2[3]);
}

__global__ __launch_bounds__(NT, 2) void gate_gemm(
    const float* __restrict__ X,
    const short* __restrict__ W1, const short* __restrict__ W2,
    const float* __restrict__ Bias, float* __restrict__ S) {
    __shared__ short lds[32768];   // 64 KiB -> 2 blocks/CU

    const int tid  = threadIdx.x;
    const int lane = tid & 63;
    const int w    = tid >> 6;        // wave 0..3
    const int wm   = w >> 1;          // 0..1 : 32-token half
    const int wn   = w & 1;           // 0..1 : 64-expert half

    // Bijective XCD swizzle (grid=512): the two expert-halves of each token
    // tile are logically adjacent -> same XCD -> X read twice but once from HBM.
    const int p       = blockIdx.x;
    const int cpx     = gridDim.x >> 3;              // 64
    const int logical = (p & 7) * cpx + (p >> 3);
    const int tok0 = (logical >> 1) * BM;
    const int e0   = (logical & 1) * BN;

    // ---- A (in registers): 32x32x16 operand: row = lane&31, k-chunk selects
    //      (lane>>5)*8 .. +7 within each 16-k. 32 floats/lane/step.
    const float* xa = X + (size_t)(tok0 + wm * 32 + (lane & 31)) * KDIM + (lane >> 5) * 8;

    // ---- B staging: 1024 16B-units per level per buffer; 4/thread/level.
    int bsrc[4], bdst[4];
#pragma unroll
    for (int j = 0; j < 4; ++j) {
        int f = j * 256 + tid;
        int e = f >> 3, pc = f & 7;
        int c = pc ^ (e & 7);
        bsrc[j] = (e0 + e) * KDIM + c * 8;   // + k0 at use (shorts)
        bdst[j] = f * 8;                     // + buf, lev at use; lane-linear x16B
    }

    // ---- B read offsets: e = wn*64 + nt*32 + (lane&31); chunk cf = ks4*2+(lane>>5)
    int bro[2][4];
#pragma unroll
    for (int nt = 0; nt < 2; ++nt) {
        int e = wn * 64 + nt * 32 + (lane & 31);
#pragma unroll
        for (int ks4 = 0; ks4 < 4; ++ks4) {
            int pc = (ks4 * 2 + (lane >> 5)) ^ (e & 7);
            bro[nt][ks4] = e * 64 + pc * 8;
        }
    }

    auto stage = [&](int bufOff, int k0) {
#pragma unroll
        for (int j = 0; j < 4; ++j) {
            load_lds16(W1 + (size_t)bsrc[j] + k0, &lds[bufOff + bdst[j]]);
            load_lds16(W2 + (size_t)bsrc[j] + k0, &lds[bufOff + 8192 + bdst[j]]);
        }
    };

    float4 raw[4][2];   // [ks4][half] : 8 floats per 16-k chunk
    auto loadA = [&](int ks) {
#pragma unroll
        for (int ks4 = 0; ks4 < 4; ++ks4) {
            const float* s = xa + (size_t)ks * BK + ks4 * 16;
            raw[ks4][0] = *(const float4*)s;
            raw[ks4][1] = *(const float4*)(s + 4);
        }
    };

    f32x16 accM[2], accC[2];
#pragma unroll
    for (int nt = 0; nt < 2; ++nt)
#pragma unroll
        for (int j = 0; j < 16; ++j) { accM[nt][j] = 0.0f; accC[nt][j] = 0.0f; }

    // ---- prologue: issue step-0 loads; first barrier pays their latency once.
    stage(0, 0);
    loadA(0);

    int buf = 0;
    for (int ks = 0; ks < NSTEP; ++ks) {
        // Barrier AT TOP: drains gll/global loads issued a full iteration ago
        // (free) and fences the buffer this iteration's stage() will overwrite.
        __syncthreads();

        if (ks + 1 < NSTEP) stage((buf ^ 1) * 16384, (ks + 1) * BK);

        // split A(ks): scaled f16 2-level, per lane
        f16x8 fa1[4], fa2[4];
#pragma unroll
        for (int ks4 = 0; ks4 < 4; ++ks4) {
            float v[8] = {raw[ks4][0].x, raw[ks4][0].y, raw[ks4][0].z, raw[ks4][0].w,
                          raw[ks4][1].x, raw[ks4][1].y, raw[ks4][1].z, raw[ks4][1].w};
#pragma unroll
            for (int j = 0; j < 8; ++j) {
                _Float16 h1 = (fabsf(v[j]) >= F16_MIN_NORMAL) ? (_Float16)v[j] : (_Float16)0.0f;
                _Float16 h2 = (_Float16)((v[j] - (float)h1) * 4096.0f);
                fa1[ks4][j] = h1;
                fa2[ks4][j] = h2;
            }
        }

        if (ks + 1 < NSTEP) loadA(ks + 1);   // A prefetch; lands well before next use

        // compute: 4 chunks x 2 nt x 3 products of 32x32x16 f16
        const int bo = buf * 16384;
#pragma unroll
        for (int nt = 0; nt < 2; ++nt) {
            f16x8 b1[4], b2[4];
#pragma unroll
            for (int ks4 = 0; ks4 < 4; ++ks4) {
                b1[ks4] = *(const f16x8*)&lds[bo + bro[nt][ks4]];
                b2[ks4] = *(const f16x8*)&lds[bo + 8192 + bro[nt][ks4]];
            }
            f32x16 cM = accM[nt], cC = accC[nt];
#pragma unroll
            for (int ks4 = 0; ks4 < 4; ++ks4) {
                cM = __builtin_amdgcn_mfma_f32_32x32x16_f16(fa1[ks4], b1[ks4], cM, 0, 0, 0);
                cC = __builtin_amdgcn_mfma_f32_32x32x16_f16(fa1[ks4], b2[ks4], cC, 0, 0, 0);
                cC = __builtin_amdgcn_mfma_f32_32x32x16_f16(fa2[ks4], b1[ks4], cC, 0, 0, 0);
            }
            accM[nt] = cM;
            accC[nt] = cC;
        }
        buf ^= 1;
    }

    // ---- epilogue: combine scales, sigmoid + bias -> scores
    // 32x32 C/D: col(expert) = lane&31, row = (reg&3) + 8*(reg>>2) + 4*(lane>>5).
#pragma unroll
    for (int nt = 0; nt < 2; ++nt) {
        const int ec = e0 + wn * 64 + nt * 32 + (lane & 31);
        const float bv = Bias[ec];
#pragma unroll
        for (int reg = 0; reg < 16; ++reg) {
            const int tr = tok0 + wm * 32 + (reg & 3) + 8 * (reg >> 2) + 4 * (lane >> 5);
            const float logit = accM[nt][reg] + accC[nt][reg] * (1.0f / 4096.0f);
            S[(size_t)tr * E_EXPERTS + ec] = 1.0f / (1.0f + expf(-logit)) + bv;
        }
    }
}

// One wave per token: 256 scores, 4/lane; 8 rounds of butterfly argmax.
// Tie-break: higher value wins; equal value -> lower index (matches lax.top_k / np).
__global__ __launch_bounds__(256) void gate_topk(
    const float* __restrict__ S, float* __restrict__ outIdx,
    float* __restrict__ outW, int T) {
    const int wave = threadIdx.x >> 6;
    const int lane = threadIdx.x & 63;
    const int t    = blockIdx.x * 4 + wave;
    if (t >= T) return;

    const float* row = S + (size_t)t * E_EXPERTS;
    float v[4];
    int   idx[4];
#pragma unroll
    for (int j = 0; j < 4; ++j) {
        idx[j] = lane + 64 * j;
        v[j]   = row[idx[j]];
    }

    float tv[TOPK];
    int   ti[TOPK];
#pragma unroll
    for (int k = 0; k < TOPK; ++k) {
        float bv = v[0];
        int   bi = idx[0];
#pragma unroll
        for (int j = 1; j < 4; ++j)
            if (v[j] > bv) { bv = v[j]; bi = idx[j]; }
#pragma unroll
        for (int off = 1; off < 64; off <<= 1) {
            float ov = __shfl_xor(bv, off);
            int   oi = __shfl_xor(bi, off);
            if (ov > bv || (ov == bv && oi < bi)) { bv = ov; bi = oi; }
        }
        tv[k] = bv;
        ti[k] = bi;
#pragma unroll
        for (int j = 0; j < 4; ++j)
            if (idx[j] == bi) v[j] = -INFINITY;
    }

    float denom = 0.0f;
#pragma unroll
    for (int k = 0; k < TOPK; ++k) denom += tv[k];
    denom += 1e-20f;

#pragma unroll
    for (int k = 0; k < TOPK; ++k) {
        if (lane == k) {
            outIdx[(size_t)t * TOPK + k] = (float)ti[k];
            outW[(size_t)t * TOPK + k]   = (tv[k] / denom) * SCALE;
        }
    }
}

extern "C" void kernel_launch(void* const* d_in, const int* in_sizes, int n_in,
                              void* d_out, int out_size, void* d_ws, size_t ws_size,
                              hipStream_t stream) {
    const float* x    = (const float*)d_in[0];
    const float* w    = (const float*)d_in[1];
    const float* bias = (const float*)d_in[2];

    const int T = in_sizes[0] / KDIM;   // 16384

    float* S  = (float*)d_ws;                                        // [T][256] f32, 16 MiB
    short* W1 = (short*)((char*)d_ws + (size_t)T * E_EXPERTS * 4);   // 2 x 2 MiB f16
    short* W2 = W1 + (size_t)E_EXPERTS * KDIM;

    float* outIdx = (float*)d_out;                  // idx chunk (as float values)
    float* outW   = outIdx + (size_t)T * TOPK;      // weight chunk

    wsplit_kernel<<<(E_EXPERTS * KDIM / 4) / 256, 256, 0, stream>>>(w, W1, W2);
    gate_gemm<<<(T / BM) * (E_EXPERTS / BN), NT, 0, stream>>>(x, W1, W2, bias, S);
    gate_topk<<<T / 4, 256, 0, stream>>>(S, outIdx, outW, T);
}